// Round 1
// baseline (435.790 us; speedup 1.0000x reference)
//
#include <hip/hip_runtime.h>
#include <math.h>

// Problem: T=4, B=2, L=2048, D=4096, fp32.
// out_t = silu(cumsum_t(x)) - silu(cumsum_{t-1}(x)), column-independent over (b,l,d).
// Memory-bound elementwise-scan: one thread per 4 consecutive inner elements,
// carries cumsum X and previous activation Yprev in registers across T=4 steps.

#define T_STEPS 4

__global__ __launch_bounds__(256) void ActSWL_kernel(const float* __restrict__ x,
                                                     float* __restrict__ out,
                                                     long long n_inner_vec,   // (B*L*D)/4
                                                     long long stride_vec) {  // (B*L*D)/4
    long long i = (long long)blockIdx.x * blockDim.x + threadIdx.x;
    if (i >= n_inner_vec) return;

    const float4* __restrict__ xv = reinterpret_cast<const float4*>(x);
    float4* __restrict__ ov       = reinterpret_cast<float4*>(out);

    float4 X     = make_float4(0.f, 0.f, 0.f, 0.f);
    float4 Yprev = make_float4(0.f, 0.f, 0.f, 0.f);

#pragma unroll
    for (int t = 0; t < T_STEPS; ++t) {
        float4 v = xv[i + (long long)t * stride_vec];

        X.x += v.x; X.y += v.y; X.z += v.z; X.w += v.w;

        float4 Y;
        Y.x = X.x / (1.0f + __expf(-X.x));
        Y.y = X.y / (1.0f + __expf(-X.y));
        Y.z = X.z / (1.0f + __expf(-X.z));
        Y.w = X.w / (1.0f + __expf(-X.w));

        float4 o;
        o.x = Y.x - Yprev.x;
        o.y = Y.y - Yprev.y;
        o.z = Y.z - Yprev.z;
        o.w = Y.w - Yprev.w;

        ov[i + (long long)t * stride_vec] = o;

        Yprev = Y;
    }
}

extern "C" void kernel_launch(void* const* d_in, const int* in_sizes, int n_in,
                              void* d_out, int out_size, void* d_ws, size_t ws_size,
                              hipStream_t stream) {
    const float* x = (const float*)d_in[0];
    float* out     = (float*)d_out;

    const long long n_total   = (long long)in_sizes[0];      // T*B*L*D = 67,108,864
    const long long n_inner   = n_total / T_STEPS;           // B*L*D  = 16,777,216
    const long long n_vec     = n_inner / 4;                 // float4 units = 4,194,304
    const long long stridev   = n_vec;                       // timestep stride in float4 units

    const int block = 256;
    const long long grid = (n_vec + block - 1) / block;      // 16384 blocks

    ActSWL_kernel<<<dim3((unsigned)grid), dim3(block), 0, stream>>>(x, out, n_vec, stridev);
}

// Round 2
// 431.707 us; speedup vs baseline: 1.0095x; 1.0095x over previous
//
#include <hip/hip_runtime.h>
#include <math.h>

// Problem: T=4, B=2, L=2048, D=4096, fp32.
// out_t = silu(cumsum_t(x)) - silu(cumsum_{t-1}(x)); columns over (b,l,d) independent.
// Pure streaming kernel: 256 MiB in + 256 MiB out, HBM-bound.
// R1: kernel ran ~3.4 TB/s. Fix: hoist all 4 timestep loads up front (MLP),
// nontemporal load/store (no reuse -> skip cache allocate), fast v_rcp_f32
// instead of IEEE divide (threshold 0.109 >> rcp error).

#define T_STEPS 4

typedef float v4f __attribute__((ext_vector_type(4)));

__device__ __forceinline__ v4f silu4(v4f X) {
    v4f r;
    // silu(x) = x / (1 + exp(-x)); __expf -> v_exp_f32, rcpf -> v_rcp_f32
    r.x = X.x * __builtin_amdgcn_rcpf(1.0f + __expf(-X.x));
    r.y = X.y * __builtin_amdgcn_rcpf(1.0f + __expf(-X.y));
    r.z = X.z * __builtin_amdgcn_rcpf(1.0f + __expf(-X.z));
    r.w = X.w * __builtin_amdgcn_rcpf(1.0f + __expf(-X.w));
    return r;
}

__global__ __launch_bounds__(256) void ActSWL_kernel(const v4f* __restrict__ xv,
                                                     v4f* __restrict__ ov,
                                                     unsigned n_vec) {  // (B*L*D)/4
    unsigned i = blockIdx.x * 256u + threadIdx.x;
    if (i >= n_vec) return;

    // Hoist all 4 loads: 4 global_load_dwordx4 in flight before any use.
    v4f v0 = __builtin_nontemporal_load(xv + i);
    v4f v1 = __builtin_nontemporal_load(xv + i + n_vec);
    v4f v2 = __builtin_nontemporal_load(xv + i + 2u * n_vec);
    v4f v3 = __builtin_nontemporal_load(xv + i + 3u * n_vec);

    v4f X  = v0;
    v4f y0 = silu4(X);
    X += v1;
    v4f y1 = silu4(X);
    X += v2;
    v4f y2 = silu4(X);
    X += v3;
    v4f y3 = silu4(X);

    __builtin_nontemporal_store(y0,      ov + i);
    __builtin_nontemporal_store(y1 - y0, ov + i + n_vec);
    __builtin_nontemporal_store(y2 - y1, ov + i + 2u * n_vec);
    __builtin_nontemporal_store(y3 - y2, ov + i + 3u * n_vec);
}

extern "C" void kernel_launch(void* const* d_in, const int* in_sizes, int n_in,
                              void* d_out, int out_size, void* d_ws, size_t ws_size,
                              hipStream_t stream) {
    const v4f* xv = (const v4f*)d_in[0];
    v4f* ov       = (v4f*)d_out;

    const long long n_total = (long long)in_sizes[0];   // T*B*L*D = 67,108,864
    const unsigned n_vec    = (unsigned)(n_total / T_STEPS / 4);  // 4,194,304 float4s

    const int block = 256;
    const unsigned grid = (n_vec + block - 1) / block;  // 16384 blocks

    ActSWL_kernel<<<dim3(grid), dim3(block), 0, stream>>>(xv, ov, n_vec);
}